// Round 20
// baseline (51.295 us; speedup 1.0000x reference)
//
#include <hip/hip_runtime.h>
#include <hip/hip_bf16.h>

#define ALPHA 0.2f
#define LOG2E 1.44269504f

// ws layout (bytes)
#define VB_OFFB 0                        // Vb: bf16 swizzled V, 6291456 B
#define XF_OFFB 6291456                  // Xf: bf16 X in A-frag order, 6291456 B
#define WB_OFFB (XF_OFFB + 6291456)      // Wb: bf16 W in B-frag order, 1179648 B
#define F1P_OFFB (WB_OFFB + 1179648)     // f1p: [4096][48] f32, 786432 B
#define F2P_OFFB (F1P_OFFB + 786432)     // f2p: [4096][48] f32, 786432 B

typedef __attribute__((ext_vector_type(8))) unsigned short us8;
typedef __attribute__((ext_vector_type(8))) short s8;
typedef __attribute__((ext_vector_type(4))) float f32x4;
typedef __attribute__((ext_vector_type(4))) unsigned int u32x4;

__device__ inline unsigned short f2bf(float x) {
    __hip_bfloat16 h = __float2bfloat16(x);
    return reinterpret_cast<unsigned short&>(h);
}

__device__ __forceinline__ void gload16(const void* g, void* lds) {
    __builtin_amdgcn_global_load_lds((const unsigned int*)g, (unsigned int*)lds,
                                     16, 0, 0);
}

// ---------------------------------------------------------------------------
// prep_all:
//   blocks 0..1535:  X fp32 -> Xf bf16 in A-FRAG order:
//     us8 index f = (rt*24 + kslot)*64 + l holds
//     X[rt*16 + (l&15)][kslot*32 + (l>>4)*8 + e], e=0..7
//     (rt = 16-row tile 0..255, kslot = K/32 step 0..23)
//   blocks 1536..1823: W fp32 -> Wb bf16 in B-frag order (verified R4).
// ---------------------------------------------------------------------------
__global__ __launch_bounds__(256) void prep_all(const float* __restrict__ X,
                                                const float* __restrict__ W,
                                                unsigned short* __restrict__ Xf,
                                                unsigned short* __restrict__ Wb) {
    if (blockIdx.x < 1536) {
        const int f = blockIdx.x * 256 + threadIdx.x;   // 0..393215
        const int l = f & 63;
        const int t = f >> 6;
        const int kslot = t % 24;
        const int rt = t / 24;
        const int row = rt * 16 + (l & 15);
        const int k0 = kslot * 32 + (l >> 4) * 8;
        const float* xp = X + (size_t)row * 768 + k0;
        float4 v0 = *(const float4*)xp;
        float4 v1 = *(const float4*)(xp + 4);
        ushort4 p0, p1;
        p0.x = f2bf(v0.x); p0.y = f2bf(v0.y); p0.z = f2bf(v0.z); p0.w = f2bf(v0.w);
        p1.x = f2bf(v1.x); p1.y = f2bf(v1.y); p1.z = f2bf(v1.z); p1.w = f2bf(v1.w);
        *(ushort4*)&Xf[(size_t)f * 8 + 0] = p0;
        *(ushort4*)&Xf[(size_t)f * 8 + 4] = p1;
    } else {
        const int id = (blockIdx.x - 1536) * 256 + threadIdx.x;
        const int l = id & 63;
        const int ks = (id >> 6) & 1;
        const int cg4 = (id >> 7) & 3;
        const int kc = id >> 9;
        const int kt = kc / 12;
        const int ct = kc - kt * 12;
        const int k0 = kt * 64 + ks * 32 + (l >> 4) * 8;
        const int n = ct * 64 + cg4 * 16 + (l & 15);
        ushort4 p0, p1;
        p0.x = f2bf(W[(size_t)(k0 + 0) * 768 + n]);
        p0.y = f2bf(W[(size_t)(k0 + 1) * 768 + n]);
        p0.z = f2bf(W[(size_t)(k0 + 2) * 768 + n]);
        p0.w = f2bf(W[(size_t)(k0 + 3) * 768 + n]);
        p1.x = f2bf(W[(size_t)(k0 + 4) * 768 + n]);
        p1.y = f2bf(W[(size_t)(k0 + 5) * 768 + n]);
        p1.z = f2bf(W[(size_t)(k0 + 6) * 768 + n]);
        p1.w = f2bf(W[(size_t)(k0 + 7) * 768 + n]);
        *(ushort4*)&Wb[(size_t)id * 8 + 0] = p0;
        *(ushort4*)&Wb[(size_t)id * 8 + 4] = p1;
    }
}

// ---------------------------------------------------------------------------
// gemm_r: BARRIER-FREE, LDS-FREE gemm. Both operands pre-swizzled into frag
// order, so every MFMA frag is ONE coalesced per-lane 16B global load
// (L2-resident after XCD swizzle). Register double-buffer over kt (static
// [kt&1] indices via full unroll); compiler pipelines with counted vmcnt —
// no s_barrier, no vmcnt(0) drains. 64x64 tile, 4 waves 2x2, grid 768.
// Epilogues: Vb swizzled store + f1p/f2p slices (both verified).
// ---------------------------------------------------------------------------
__global__ __launch_bounds__(256) void gemm_r(const unsigned short* __restrict__ Xf_,
                                              const unsigned short* __restrict__ Wb_,
                                              const float* __restrict__ a,
                                              unsigned short* __restrict__ Vb,
                                              float* __restrict__ f1p,
                                              float* __restrict__ f2p) {
    const int tid = threadIdx.x;
    const int l = tid & 63;
    const int w = tid >> 6;
    const int wr = w >> 1, wc = w & 1;
    const int nid = (blockIdx.x & 7) * 96 + (blockIdx.x >> 3);  // XCD swizzle
    const int bx = nid % 12;             // N-tile (64 cols)
    const int row0 = (nid / 12) * 64;    // M-tile (64 rows)
    const int rt0 = (nid / 12) * 4;      // 16-row tile base

    const us8* Xf = (const us8*)Xf_;
    const us8* Wf = (const us8*)Wb_;

    // A-frag base for fr in {0,1}: frag (rt, kslot) at (rt*24 + kslot)*64 + l
    const us8* xb0 = Xf + ((size_t)(rt0 + wr * 2 + 0) * 24) * 64 + l;
    const us8* xb1 = Xf + ((size_t)(rt0 + wr * 2 + 1) * 24) * 64 + l;
    // B-frag base: frag (kt, cg, ks) at (kt*12+bx)*512 + (wc*2+cg)*128 + ks*64 + l
    const us8* wb0 = Wf + (size_t)bx * 512 + (size_t)(wc * 2) * 128 + l;

    f32x4 acc[2][2];
#pragma unroll
    for (int i = 0; i < 2; ++i)
#pragma unroll
        for (int j = 0; j < 2; ++j) acc[i][j] = (f32x4){0.f, 0.f, 0.f, 0.f};

    s8 af[2][2][2];   // [buf][fr][ks]
    s8 bf[2][2][2];   // [buf][cg][ks]

    // prologue: kt=0 -> buf 0
#pragma unroll
    for (int ks = 0; ks < 2; ++ks) {
        af[0][0][ks] = (s8)xb0[ks * 64];
        af[0][1][ks] = (s8)xb1[ks * 64];
        bf[0][0][ks] = (s8)wb0[ks * 64];
        bf[0][1][ks] = (s8)wb0[128 + ks * 64];
    }

#pragma unroll
    for (int kt = 0; kt < 12; ++kt) {
        const int cur = kt & 1;
        const int nxt = cur ^ 1;
        if (kt < 11) {
            const int kn = kt + 1;
#pragma unroll
            for (int ks = 0; ks < 2; ++ks) {
                af[nxt][0][ks] = (s8)xb0[(kn * 2 + ks) * 64];
                af[nxt][1][ks] = (s8)xb1[(kn * 2 + ks) * 64];
                bf[nxt][0][ks] = (s8)wb0[(size_t)kn * 6144 + ks * 64];
                bf[nxt][1][ks] = (s8)wb0[(size_t)kn * 6144 + 128 + ks * 64];
            }
        }
#pragma unroll
        for (int ks = 0; ks < 2; ++ks)
#pragma unroll
            for (int fr = 0; fr < 2; ++fr)
#pragma unroll
                for (int cg = 0; cg < 2; ++cg)
                    acc[fr][cg] = __builtin_amdgcn_mfma_f32_16x16x32_bf16(
                        af[cur][fr][ks], bf[cur][cg][ks], acc[fr][cg], 0, 0, 0);
    }

    // Epilogue 1: Vb swizzled bf16 store. C/D: col=l&15, row=(l>>4)*4+reg.
#pragma unroll
    for (int fr = 0; fr < 2; ++fr) {
#pragma unroll
        for (int cg = 0; cg < 2; ++cg) {
            const int jglob = row0 + wr * 32 + fr * 16 + (l >> 4) * 4;
            const int b = jglob >> 10;
            const int jn = jglob & 1023;
            const int jc = jn >> 7;
            const int ks4 = (jn >> 5) & 3;
            const int kg = (jn >> 3) & 3;
            const int e0 = jn & 7;
            const int g0 = bx * 64 + wc * 32 + cg * 16;
            const int h = g0 / 96;
            const int ft = (g0 - h * 96) >> 4;
            const int fc = l & 15;
            const size_t ibase =
                (((((size_t)(b * 8 + h) * 8 + jc) * 4 + ks4) * 4 + kg) * 6 + ft) * 128 +
                fc * 8 + e0;
            ushort4 pk;
            pk.x = f2bf(acc[fr][cg][0]);
            pk.y = f2bf(acc[fr][cg][1]);
            pk.z = f2bf(acc[fr][cg][2]);
            pk.w = f2bf(acc[fr][cg][3]);
            *(ushort4*)&Vb[ibase] = pk;
        }
    }

    // Epilogue 2: f1p/f2p slices (no atomics; unique writer per (row,g)).
#pragma unroll
    for (int cg = 0; cg < 2; ++cg) {
        const int c = bx * 64 + wc * 32 + cg * 16 + (l & 15);
        const int h = c / 96;
        const int f = c - h * 96;
        const float av1 = a[f];
        const float av2 = a[96 + f];
        const int g = bx * 4 + wc * 2 + cg;
#pragma unroll
        for (int fr = 0; fr < 2; ++fr) {
            const int jglob = row0 + wr * 32 + fr * 16 + (l >> 4) * 4;
#pragma unroll
            for (int r = 0; r < 4; ++r) {
                float s1 = acc[fr][cg][r] * av1;
                float s2 = acc[fr][cg][r] * av2;
#pragma unroll
                for (int m = 1; m < 16; m <<= 1) {
                    s1 += __shfl_xor(s1, m);
                    s2 += __shfl_xor(s2, m);
                }
                if ((l & 15) == 0) {
                    f1p[(size_t)(jglob + r) * 48 + g] = s1;
                    f2p[(size_t)(jglob + r) * 48 + g] = s2;
                }
            }
        }
    }
}

// ---------------------------------------------------------------------------
// attn_fast: R18 (kept): old dbuf sync, fast P path (fmaxf LeakyReLU +
// v_cvt_pk_bf16_f32 packed conversion), slice-sum prologue.
// ---------------------------------------------------------------------------
__global__ __launch_bounds__(256) void attn_fast(const unsigned short* __restrict__ Vb,
                                                 const float* __restrict__ f1p,
                                                 const float* __restrict__ f2p,
                                                 const int* __restrict__ mask,
                                                 float* __restrict__ out) {
    __shared__ __align__(16) unsigned short Vs[2][12288];
    __shared__ float g2_s[1024];

    const int tid = threadIdx.x;
    const int lane = tid & 63;
    const int w = tid >> 6;
    const int kg = lane >> 4;
    const int fcr = lane & 15;
    const int nid = (blockIdx.x & 7) * 64 + (blockIdx.x >> 3);
    const int it = nid & 15;       // 16 i-tiles of 64 rows
    const int bh = nid >> 4;
    const int b = bh >> 3;
    const int h = bh & 7;

    const size_t vbase = (size_t)bh * 98304;

    for (int j = tid; j < 1024; j += 256) {
        const float* p2 = f2p + (size_t)(b * 1024 + j) * 48 + h * 6;
        float s = ((p2[0] + p2[1]) + (p2[2] + p2[3])) + (p2[4] + p2[5]);
        g2_s[j] = (mask[b * 1024 + j] != 0) ? s * LOG2E : -20000.f;
    }
    const float* p1 = f1p + (size_t)(b * 1024 + it * 64 + w * 16 + fcr) * 48 + h * 6;
    const float f1v = (((p1[0] + p1[1]) + (p1[2] + p1[3])) + (p1[4] + p1[5])) * LOG2E;

#pragma unroll
    for (int r = 0; r < 6; ++r) {
        const int s = r * 256 + tid;           // 16B slot 0..1535
        gload16(Vb + vbase + (size_t)s * 8, &Vs[0][s * 8]);
    }

    f32x4 acc[6];
#pragma unroll
    for (int ft = 0; ft < 6; ++ft) acc[ft] = (f32x4){0.f, 0.f, 0.f, 0.f};
    float ls = 0.f;

    int buf = 0;
    for (int c = 0; c < 8; ++c) {
        __syncthreads();
        if (c < 7) {
#pragma unroll
            for (int r = 0; r < 6; ++r) {
                const int s = r * 256 + tid;
                gload16(Vb + vbase + (size_t)(c + 1) * 12288 + (size_t)s * 8,
                        &Vs[buf ^ 1][s * 8]);
            }
        }
        const unsigned short* vsb = &Vs[buf][0];
#pragma unroll
        for (int ks = 0; ks < 4; ++ks) {
            const int jb = c * 128 + ks * 32 + kg * 8;
            float4 ga = *(const float4*)&g2_s[jb];
            float4 gb = *(const float4*)&g2_s[jb + 4];
            float g[8] = {ga.x, ga.y, ga.z, ga.w, gb.x, gb.y, gb.z, gb.w};
            u32x4 afu;
#pragma unroll
            for (int ep = 0; ep < 4; ++ep) {
                float t0 = f1v + g[2 * ep];
                float t1 = f1v + g[2 * ep + 1];
                float l0 = fmaxf(t0, ALPHA * t0);   // LeakyReLU (log2 domain)
                float l1 = fmaxf(t1, ALPHA * t1);
                float p0 = exp2f(l0);
                float p1 = exp2f(l1);
                ls += p0 + p1;
                unsigned int pk;
                asm("v_cvt_pk_bf16_f32 %0, %1, %2" : "=v"(pk) : "v"(p0), "v"(p1));
                afu[ep] = pk;
            }
            s8 af = __builtin_bit_cast(s8, afu);
            const unsigned short* vp = vsb + ((ks * 4 + kg) * 6) * 128 + fcr * 8;
#pragma unroll
            for (int ft = 0; ft < 6; ++ft) {
                us8 bvu = *(const us8*)(vp + ft * 128);
                acc[ft] = __builtin_amdgcn_mfma_f32_16x16x32_bf16(
                    af, (s8)bvu, acc[ft], 0, 0, 0);
            }
        }
        buf ^= 1;
    }

    ls += __shfl_xor(ls, 16);
    ls += __shfl_xor(ls, 32);
    float inv[4];
#pragma unroll
    for (int r = 0; r < 4; ++r) inv[r] = 1.0f / __shfl(ls, kg * 4 + r);

    const int irow0 = it * 64 + w * 16 + kg * 4;
#pragma unroll
    for (int r = 0; r < 4; ++r) {
        const size_t ob = (size_t)(b * 1024 + irow0 + r) * 768 + h * 96 + fcr;
#pragma unroll
        for (int ft = 0; ft < 6; ++ft) {
            out[ob + ft * 16] = acc[ft][r] * inv[r];
        }
    }
}

extern "C" void kernel_launch(void* const* d_in, const int* in_sizes, int n_in,
                              void* d_out, int out_size, void* d_ws, size_t ws_size,
                              hipStream_t stream) {
    const float* X = (const float*)d_in[0];
    const int* mask = (const int*)d_in[1];
    const float* W = (const float*)d_in[2];
    const float* a = (const float*)d_in[3];
    float* out = (float*)d_out;
    char* ws = (char*)d_ws;

    unsigned short* Vb = (unsigned short*)(ws + VB_OFFB);
    unsigned short* Xf = (unsigned short*)(ws + XF_OFFB);
    unsigned short* Wb = (unsigned short*)(ws + WB_OFFB);
    float* f1p = (float*)(ws + F1P_OFFB);
    float* f2p = (float*)(ws + F2P_OFFB);

    prep_all<<<1824, 256, 0, stream>>>(X, W, Xf, Wb);
    gemm_r<<<768, 256, 0, stream>>>(Xf, Wb, a, Vb, f1p, f2p);
    attn_fast<<<512, 256, 0, stream>>>(Vb, f1p, f2p, mask, out);
}

// Round 21
// 50.013 us; speedup vs baseline: 1.0256x; 1.0256x over previous
//
#include <hip/hip_runtime.h>
#include <hip/hip_bf16.h>

#define ALPHA 0.2f
#define LOG2E 1.44269504f

// ws layout (bytes)
#define VB_OFFB 0                        // Vb: bf16 swizzled V, 6291456 B
#define XB_OFFB 6291456                  // Xb: bf16 X, 6291456 B
#define WB_OFFB (XB_OFFB + 6291456)      // Wb: bf16 swizzled W, 1179648 B
#define F1P_OFFB (WB_OFFB + 1179648)     // f1p: [4096][48] f32, 786432 B
#define F2P_OFFB (F1P_OFFB + 786432)     // f2p: [4096][48] f32, 786432 B

typedef __attribute__((ext_vector_type(8))) unsigned short us8;
typedef __attribute__((ext_vector_type(8))) short s8;
typedef __attribute__((ext_vector_type(4))) float f32x4;
typedef __attribute__((ext_vector_type(4))) unsigned int u32x4;

__device__ inline unsigned short f2bf(float x) {
    __hip_bfloat16 h = __float2bfloat16(x);
    return reinterpret_cast<unsigned short&>(h);
}

__device__ __forceinline__ void gload16(const void* g, void* lds) {
    __builtin_amdgcn_global_load_lds((const unsigned int*)g, (unsigned int*)lds,
                                     16, 0, 0);
}

// ---------------------------------------------------------------------------
// prep_all: blocks 0..1535: X -> Xb bf16; 1536..1823: W -> Wb B-frag order.
// ---------------------------------------------------------------------------
__global__ __launch_bounds__(256) void prep_all(const float* __restrict__ X,
                                                const float* __restrict__ W,
                                                unsigned short* __restrict__ Xb,
                                                unsigned short* __restrict__ Wb) {
    if (blockIdx.x < 1536) {
        const int i = (blockIdx.x * 256 + threadIdx.x) * 8;
        float4 v0 = *(const float4*)&X[i];
        float4 v1 = *(const float4*)&X[i + 4];
        ushort4 p0, p1;
        p0.x = f2bf(v0.x); p0.y = f2bf(v0.y); p0.z = f2bf(v0.z); p0.w = f2bf(v0.w);
        p1.x = f2bf(v1.x); p1.y = f2bf(v1.y); p1.z = f2bf(v1.z); p1.w = f2bf(v1.w);
        *(ushort4*)&Xb[i] = p0;
        *(ushort4*)&Xb[i + 4] = p1;
    } else {
        const int id = (blockIdx.x - 1536) * 256 + threadIdx.x;
        const int l = id & 63;
        const int ks = (id >> 6) & 1;
        const int cg4 = (id >> 7) & 3;
        const int kc = id >> 9;
        const int kt = kc / 12;
        const int ct = kc - kt * 12;
        const int k0 = kt * 64 + ks * 32 + (l >> 4) * 8;
        const int n = ct * 64 + cg4 * 16 + (l & 15);
        ushort4 p0, p1;
        p0.x = f2bf(W[(size_t)(k0 + 0) * 768 + n]);
        p0.y = f2bf(W[(size_t)(k0 + 1) * 768 + n]);
        p0.z = f2bf(W[(size_t)(k0 + 2) * 768 + n]);
        p0.w = f2bf(W[(size_t)(k0 + 3) * 768 + n]);
        p1.x = f2bf(W[(size_t)(k0 + 4) * 768 + n]);
        p1.y = f2bf(W[(size_t)(k0 + 5) * 768 + n]);
        p1.z = f2bf(W[(size_t)(k0 + 6) * 768 + n]);
        p1.w = f2bf(W[(size_t)(k0 + 7) * 768 + n]);
        *(ushort4*)&Wb[(size_t)id * 8 + 0] = p0;
        *(ushort4*)&Wb[(size_t)id * 8 + 4] = p1;
    }
}

// ---------------------------------------------------------------------------
// gemm32: 32x64 M-tile gemm (R19, best measured). Grid 1536, 24 KB LDS,
// 6 blocks/CU. Same verified staging swizzle and epilogues.
// ---------------------------------------------------------------------------
__global__ __launch_bounds__(256) void gemm32(const unsigned short* __restrict__ Xb,
                                              const unsigned short* __restrict__ Wb,
                                              const float* __restrict__ a,
                                              unsigned short* __restrict__ Vb,
                                              float* __restrict__ f1p,
                                              float* __restrict__ f2p) {
    __shared__ __align__(16) unsigned short Xs[2][2048];   // 32 rows x 64 k
    __shared__ __align__(16) unsigned short Ws[2][4096];   // 64 k x 64 n

    const int tid = threadIdx.x;
    const int l = tid & 63;
    const int w = tid >> 6;
    const int wr = w >> 1, wc = w & 1;
    const int nid = (blockIdx.x & 7) * 192 + (blockIdx.x >> 3);  // XCD swizzle
    const int bx = nid % 12;             // N-tile (64 cols)
    const int row0 = (nid / 12) * 32;    // M-tile (32 rows)

    const int xrow = w * 8 + (l >> 3);
    const int xkb_log8 = ((l & 7) ^ (l >> 3)) * 8;

    f32x4 acc[2];
#pragma unroll
    for (int j = 0; j < 2; ++j) acc[j] = (f32x4){0.f, 0.f, 0.f, 0.f};

    {
        gload16(Xb + (size_t)(row0 + xrow) * 768 + xkb_log8, &Xs[0][w * 512]);
#pragma unroll
        for (int q = 0; q < 2; ++q) {
            const int g16 = w * 2 + q;
            gload16(Wb + (size_t)(0 * 12 + bx) * 4096 + g16 * 512 + l * 8,
                    &Ws[0][g16 * 512]);
        }
    }

    int buf = 0;
    for (int kt = 0; kt < 12; ++kt) {
        __syncthreads();
        if (kt < 11) {
            const int k0n = (kt + 1) * 64;
            gload16(Xb + (size_t)(row0 + xrow) * 768 + k0n + xkb_log8,
                    &Xs[buf ^ 1][w * 512]);
#pragma unroll
            for (int q = 0; q < 2; ++q) {
                const int g16 = w * 2 + q;
                gload16(Wb + (size_t)((kt + 1) * 12 + bx) * 4096 + g16 * 512 + l * 8,
                        &Ws[buf ^ 1][g16 * 512]);
            }
        }
#pragma unroll
        for (int ks = 0; ks < 2; ++ks) {
            s8 af, bfr[2];
            {
                const int row = wr * 16 + (l & 15);
                const int slot = (ks * 4 + (l >> 4)) ^ (row & 7);
                af = *(const s8*)((const char*)&Xs[buf][0] + row * 128 + slot * 16);
            }
#pragma unroll
            for (int cg = 0; cg < 2; ++cg) {
                bfr[cg] = *(const s8*)((const char*)&Ws[buf][0] +
                                       (((wc * 2 + cg) * 2 + ks) * 64 + l) * 16);
            }
#pragma unroll
            for (int cg = 0; cg < 2; ++cg)
                acc[cg] = __builtin_amdgcn_mfma_f32_16x16x32_bf16(
                    af, bfr[cg], acc[cg], 0, 0, 0);
        }
        buf ^= 1;
    }

    // Epilogue 1: Vb swizzled bf16 store. C/D: col=l&15, row=(l>>4)*4+reg.
#pragma unroll
    for (int cg = 0; cg < 2; ++cg) {
        const int jglob = row0 + wr * 16 + (l >> 4) * 4;
        const int b = jglob >> 10;
        const int jn = jglob & 1023;
        const int jc = jn >> 7;
        const int ks4 = (jn >> 5) & 3;
        const int kg = (jn >> 3) & 3;
        const int e0 = jn & 7;
        const int g0 = bx * 64 + wc * 32 + cg * 16;
        const int h = g0 / 96;
        const int ft = (g0 - h * 96) >> 4;
        const int fc = l & 15;
        const size_t ibase =
            (((((size_t)(b * 8 + h) * 8 + jc) * 4 + ks4) * 4 + kg) * 6 + ft) * 128 +
            fc * 8 + e0;
        ushort4 pk;
        pk.x = f2bf(acc[cg][0]);
        pk.y = f2bf(acc[cg][1]);
        pk.z = f2bf(acc[cg][2]);
        pk.w = f2bf(acc[cg][3]);
        *(ushort4*)&Vb[ibase] = pk;
    }

    // Epilogue 2: f1p/f2p slices (no atomics; unique writer per (row,g)).
#pragma unroll
    for (int cg = 0; cg < 2; ++cg) {
        const int c = bx * 64 + wc * 32 + cg * 16 + (l & 15);
        const int h = c / 96;
        const int f = c - h * 96;
        const float av1 = a[f];
        const float av2 = a[96 + f];
        const int g = bx * 4 + wc * 2 + cg;
        const int jglob = row0 + wr * 16 + (l >> 4) * 4;
#pragma unroll
        for (int r = 0; r < 4; ++r) {
            float s1 = acc[cg][r] * av1;
            float s2 = acc[cg][r] * av2;
#pragma unroll
            for (int m = 1; m < 16; m <<= 1) {
                s1 += __shfl_xor(s1, m);
                s2 += __shfl_xor(s2, m);
            }
            if ((l & 15) == 0) {
                f1p[(size_t)(jglob + r) * 48 + g] = s1;
                f2p[(size_t)(jglob + r) * 48 + g] = s2;
            }
        }
    }
}

// ---------------------------------------------------------------------------
// attn_fast: old dbuf sync, fast P path (fmaxf LeakyReLU + v_cvt_pk_bf16_f32
// packed conversion), slice-sum prologue. (R18/R19 verified)
// ---------------------------------------------------------------------------
__global__ __launch_bounds__(256) void attn_fast(const unsigned short* __restrict__ Vb,
                                                 const float* __restrict__ f1p,
                                                 const float* __restrict__ f2p,
                                                 const int* __restrict__ mask,
                                                 float* __restrict__ out) {
    __shared__ __align__(16) unsigned short Vs[2][12288];
    __shared__ float g2_s[1024];

    const int tid = threadIdx.x;
    const int lane = tid & 63;
    const int w = tid >> 6;
    const int kg = lane >> 4;
    const int fcr = lane & 15;
    const int nid = (blockIdx.x & 7) * 64 + (blockIdx.x >> 3);
    const int it = nid & 15;       // 16 i-tiles of 64 rows
    const int bh = nid >> 4;
    const int b = bh >> 3;
    const int h = bh & 7;

    const size_t vbase = (size_t)bh * 98304;

    for (int j = tid; j < 1024; j += 256) {
        const float* p2 = f2p + (size_t)(b * 1024 + j) * 48 + h * 6;
        float s = ((p2[0] + p2[1]) + (p2[2] + p2[3])) + (p2[4] + p2[5]);
        g2_s[j] = (mask[b * 1024 + j] != 0) ? s * LOG2E : -20000.f;
    }
    const float* p1 = f1p + (size_t)(b * 1024 + it * 64 + w * 16 + fcr) * 48 + h * 6;
    const float f1v = (((p1[0] + p1[1]) + (p1[2] + p1[3])) + (p1[4] + p1[5])) * LOG2E;

#pragma unroll
    for (int r = 0; r < 6; ++r) {
        const int s = r * 256 + tid;           // 16B slot 0..1535
        gload16(Vb + vbase + (size_t)s * 8, &Vs[0][s * 8]);
    }

    f32x4 acc[6];
#pragma unroll
    for (int ft = 0; ft < 6; ++ft) acc[ft] = (f32x4){0.f, 0.f, 0.f, 0.f};
    float ls = 0.f;

    int buf = 0;
    for (int c = 0; c < 8; ++c) {
        __syncthreads();
        if (c < 7) {
#pragma unroll
            for (int r = 0; r < 6; ++r) {
                const int s = r * 256 + tid;
                gload16(Vb + vbase + (size_t)(c + 1) * 12288 + (size_t)s * 8,
                        &Vs[buf ^ 1][s * 8]);
            }
        }
        const unsigned short* vsb = &Vs[buf][0];
#pragma unroll
        for (int ks = 0; ks < 4; ++ks) {
            const int jb = c * 128 + ks * 32 + kg * 8;
            float4 ga = *(const float4*)&g2_s[jb];
            float4 gb = *(const float4*)&g2_s[jb + 4];
            float g[8] = {ga.x, ga.y, ga.z, ga.w, gb.x, gb.y, gb.z, gb.w};
            u32x4 afu;
#pragma unroll
            for (int ep = 0; ep < 4; ++ep) {
                float t0 = f1v + g[2 * ep];
                float t1 = f1v + g[2 * ep + 1];
                float l0 = fmaxf(t0, ALPHA * t0);   // LeakyReLU (log2 domain)
                float l1 = fmaxf(t1, ALPHA * t1);
                float p0 = exp2f(l0);
                float p1 = exp2f(l1);
                ls += p0 + p1;
                unsigned int pk;
                asm("v_cvt_pk_bf16_f32 %0, %1, %2" : "=v"(pk) : "v"(p0), "v"(p1));
                afu[ep] = pk;
            }
            s8 af = __builtin_bit_cast(s8, afu);
            const unsigned short* vp = vsb + ((ks * 4 + kg) * 6) * 128 + fcr * 8;
#pragma unroll
            for (int ft = 0; ft < 6; ++ft) {
                us8 bvu = *(const us8*)(vp + ft * 128);
                acc[ft] = __builtin_amdgcn_mfma_f32_16x16x32_bf16(
                    af, (s8)bvu, acc[ft], 0, 0, 0);
            }
        }
        buf ^= 1;
    }

    ls += __shfl_xor(ls, 16);
    ls += __shfl_xor(ls, 32);
    float inv[4];
#pragma unroll
    for (int r = 0; r < 4; ++r) inv[r] = 1.0f / __shfl(ls, kg * 4 + r);

    const int irow0 = it * 64 + w * 16 + kg * 4;
#pragma unroll
    for (int r = 0; r < 4; ++r) {
        const size_t ob = (size_t)(b * 1024 + irow0 + r) * 768 + h * 96 + fcr;
#pragma unroll
        for (int ft = 0; ft < 6; ++ft) {
            out[ob + ft * 16] = acc[ft][r] * inv[r];
        }
    }
}

extern "C" void kernel_launch(void* const* d_in, const int* in_sizes, int n_in,
                              void* d_out, int out_size, void* d_ws, size_t ws_size,
                              hipStream_t stream) {
    const float* X = (const float*)d_in[0];
    const int* mask = (const int*)d_in[1];
    const float* W = (const float*)d_in[2];
    const float* a = (const float*)d_in[3];
    float* out = (float*)d_out;
    char* ws = (char*)d_ws;

    unsigned short* Vb = (unsigned short*)(ws + VB_OFFB);
    unsigned short* Xb = (unsigned short*)(ws + XB_OFFB);
    unsigned short* Wb = (unsigned short*)(ws + WB_OFFB);
    float* f1p = (float*)(ws + F1P_OFFB);
    float* f2p = (float*)(ws + F2P_OFFB);

    prep_all<<<1824, 256, 0, stream>>>(X, W, Xb, Wb);
    gemm32<<<1536, 256, 0, stream>>>(Xb, Wb, a, Vb, f1p, f2p);
    attn_fast<<<512, 256, 0, stream>>>(Vb, f1p, f2p, mask, out);
}